// Round 12
// baseline (198.624 us; speedup 1.0000x reference)
//
#include <hip/hip_runtime.h>

// LocalEnergy R22: R15 exact (harness-verified best, 54.8us) with ONE change:
// GEMM2 decomposition flipped from hid-split (each wave: all 128 rows x 32
// cols, reading the ENTIRE 32KB H1s per type) to row-split (each wave: its
// own 32 rows x all 128 cols). A-fragments = 8 ds_read_b128 (8KB) held in 32
// VGPRs and reused across 4 col-tiles -> GEMM2 LDS reads drop 4x (the
// largest LDS-pipe consumer, ~15us/CU). B2 streams 32KB/wave/type from ws
// but all waves traverse the same W2T -> L1-resident. MFMA count, fragment
// mappings, XOR swizzle, prologue, barrier placement identical to R15.
// Peak regs ~100 < 128 cap of (256,4). B=128, L=2048, E=16, H=128.

typedef short bf16x8  __attribute__((ext_vector_type(8)));
typedef float f32x4   __attribute__((ext_vector_type(4)));
typedef float f32x16  __attribute__((ext_vector_type(16)));

constexpr int Lc  = 2048;

union FragU { uint4 u; bf16x8 v; };

__device__ __forceinline__ unsigned short f2bf(float f) {
    union { float f; unsigned u; } v; v.f = f;
    unsigned u = v.u;
    u = u + 0x7FFFu + ((u >> 16) & 1u);   // RTNE
    return (unsigned short)(u >> 16);
}

__device__ __forceinline__ unsigned pkbf(float a, float b) {
    unsigned ua = __float_as_uint(a) + 0x8000u;
    unsigned ub = __float_as_uint(b) + 0x8000u;
    return __builtin_amdgcn_perm(ub, ua, 0x07060302u);  // [lo=bf(a), hi=bf(b)]
}

// ws layout (bytes) — unchanged from R11/R15:
//   W2T[t] @ t*32768          : [col2=128][k=128] bf16 k-contig      (98304)
//   W1T[t] @ 98304 + t*24576  : [hid=128][k=96]   bf16 k-contig      (73728)
//     header slots: k0=len(t0), k1=cos_t(t1), k2=sin_p(t2), k3=cos_p(t2),
//     k4=b1, k16+j = embedding row j
//   EB     @ 172032           : [aa=20][16] bf16                     (640)
__global__ __launch_bounds__(256)
void prep_kernel(const float* __restrict__ W1_0, const float* __restrict__ b1_0,
                 const float* __restrict__ W1_1, const float* __restrict__ b1_1,
                 const float* __restrict__ W1_2, const float* __restrict__ b1_2,
                 const float* __restrict__ W2_0, const float* __restrict__ W2_1,
                 const float* __restrict__ W2_2,
                 const float* __restrict__ emb, char* __restrict__ ws,
                 float* __restrict__ out)
{
    const int tid = blockIdx.x * 256 + threadIdx.x;
    const int np  = gridDim.x * 256;
    if (blockIdx.x == 0 && threadIdx.x < 128) out[threadIdx.x] = 0.0f;

    unsigned short* d2 = (unsigned short*)ws;
    for (int o = tid; o < 3 * 16384; o += np) {
        int t = o >> 14, r = o & 16383, col = r >> 7, k = r & 127;
        const float* W2 = (t == 0) ? W2_0 : (t == 1) ? W2_1 : W2_2;
        d2[o] = f2bf(W2[k * 128 + col]);
    }
    unsigned short* d1 = (unsigned short*)(ws + 98304);
    for (int o = tid; o < 3 * 12288; o += np) {
        int t = o / 12288, r = o - t * 12288, hid = r / 96, k = r - hid * 96;
        const int NE16 = (t == 0) ? 32 : (t == 1) ? 48 : 64;
        const int NG   = (t == 2) ? 2 : 1;
        const float* W1 = (t == 0) ? W1_0 : (t == 1) ? W1_1 : W1_2;
        const float* b1 = (t == 0) ? b1_0 : (t == 1) ? b1_1 : b1_2;
        float v = 0.0f;
        if (k >= 16) {
            int j = k - 16;
            if (j < NE16) v = W1[(NG + j) * 128 + hid];
        } else if (k == 4) v = b1[hid];
        else if (t == 0 && k == 0) v = W1_0[hid];
        else if (t == 1 && k == 1) v = W1_1[hid];
        else if (t == 2 && k == 2) v = W1_2[hid];
        else if (t == 2 && k == 3) v = W1_2[128 + hid];
        d1[o] = f2bf(v);
    }
    unsigned short* eb = (unsigned short*)(ws + 172032);
    for (int i = tid; i < 320; i += np) eb[i] = f2bf(emb[i]);
}

struct SMem {
    unsigned short H1s[128 * 128];  // 32768 B, row stride 256B, XOR-swizzled
    float  Rbuf[393];               // 131 rows x 3
    uint2  geomh[128];              // packed bf16 header per row
    int    seqb[132];
    alignas(16) unsigned short ebuf[320];   // [20][16] bf16
    float  part[4];
};

// swizzled byte offset of H1[row][byte col]
__device__ __forceinline__ int h1_off(int row, int colb) {
    return row * 256 + (colb ^ ((row & 15) << 4));
}

template<int TYPE>
__device__ __forceinline__ void type_pass(
    SMem& sm, const char* __restrict__ ws,
    const float* __restrict__ b2, const float* __restrict__ w3,
    int i0, int wv, int ln31, int hi, f32x4& p4)
{
    constexpr int NEMB  = (TYPE == 0) ? 2 : (TYPE == 1) ? 3 : 4;
    constexpr int STEPS = 1 + NEMB;          // header + emb K-steps (K=16 each)
    constexpr int ROWSB = Lc - 1 - TYPE;

    const unsigned short* w1t = (const unsigned short*)(ws + 98304 + TYPE * 24576);
    const unsigned short* w2t = (const unsigned short*)(ws + TYPE * 32768);
    const f32x4 z4 = (f32x4){0.f, 0.f, 0.f, 0.f};

    // A1 frags: W1T[m=hid=wv*32+ln31][k=s*16+hi*8 ..+8]  (L2-hot)
    FragU A1[STEPS];
#pragma unroll
    for (int s = 0; s < STEPS; ++s)
        A1[s].u = *(const uint4*)&w1t[(wv * 32 + ln31) * 96 + s * 16 + hi * 8];

    // ---- Phase 1: GEMM1 over both 64-row halves (acc regs reused) ----
#pragma unroll
    for (int h = 0; h < 2; ++h) {
        f32x16 acc1[2];
        acc1[0] = (f32x16)(0.f);
        acc1[1] = (f32x16)(0.f);

#pragma unroll
        for (int s = 0; s < STEPS; ++s) {
#pragma unroll
            for (int rt = 0; rt < 2; ++rt) {
                const int row = h * 64 + rt * 32 + ln31;
                FragU bb;
                if (s == 0) {                      // header [len,cos_t,sin_p,cos_p,1,0..]
                    if (hi == 0) {
                        uint2 g = sm.geomh[row];
                        bb.u = make_uint4(g.x, g.y, 0x00003F80u, 0u);
                    } else {
                        bb.u = make_uint4(0u, 0u, 0u, 0u);
                    }
                } else {                           // embedding row j = s-1
                    bb.u = *(const uint4*)&sm.ebuf[sm.seqb[row + (s - 1)] * 16 + hi * 8];
                }
                acc1[rt] = __builtin_amdgcn_mfma_f32_32x32x16_bf16(A1[s].v, bb.v, acc1[rt], 0, 0, 0);
            }
        }

        // H1 = relu -> H1s (swizzled). D: col=ln31=row, hid=(reg&3)+8*(reg>>2)+4*hi.
#pragma unroll
        for (int rt = 0; rt < 2; ++rt) {
            const int row = h * 64 + rt * 32 + ln31;
#pragma unroll
            for (int g = 0; g < 4; ++g) {
                float v0 = fmaxf(acc1[rt][4 * g + 0], 0.f);
                float v1 = fmaxf(acc1[rt][4 * g + 1], 0.f);
                float v2 = fmaxf(acc1[rt][4 * g + 2], 0.f);
                float v3 = fmaxf(acc1[rt][4 * g + 3], 0.f);
                uint2 pk;
                pk.x = pkbf(v0, v1);
                pk.y = pkbf(v2, v3);
                *(uint2*)((char*)sm.H1s + h1_off(row, wv * 64 + 16 * g + 8 * hi)) = pk;
            }
        }
    }

    __syncthreads();   // H1s (all 128 rows) ready

    // ---- Phase 2: GEMM2 row-split — this wave's 32 rows x all 128 cols ----
    // A frags: own quarter of H1 (8 x ds_read_b128 = 8KB), held across all
    // 4 col-tiles (32 VGPRs). B2 streams per col-tile from L1/L2.
    FragU a2f[8];
#pragma unroll
    for (int s2 = 0; s2 < 8; ++s2)
        a2f[s2].u = *(const uint4*)((const char*)sm.H1s +
                                    h1_off(wv * 32 + ln31, s2 * 32 + hi * 16));

#pragma unroll
    for (int ct = 0; ct < 4; ++ct) {
        FragU B2[8];
#pragma unroll
        for (int s2 = 0; s2 < 8; ++s2)
            B2[s2].u = *(const uint4*)&w2t[(ct * 32 + ln31) * 128 + s2 * 16 + hi * 8];
        const float b2v = b2[ct * 32 + ln31];
        const float w3v = w3[ct * 32 + ln31];

        f32x16 acc2 = (f32x16)(0.f);
#pragma unroll
        for (int s2 = 0; s2 < 8; ++s2)
            acc2 = __builtin_amdgcn_mfma_f32_32x32x16_bf16(a2f[s2].v, B2[s2].v, acc2, 0, 0, 0);

        // epilogue: p4 += relu(h2 + b2) * w3. D: col=ln31 (col2 = ct*32+ln31),
        // row = wv*32 + (reg&3) + 8*(reg>>2) + 4*hi.
#pragma unroll
        for (int g = 0; g < 4; ++g) {
            const int rbase = i0 + wv * 32 + 8 * g + 4 * hi;
            f32x4 v;
            v[0] = acc2[4 * g + 0]; v[1] = acc2[4 * g + 1];
            v[2] = acc2[4 * g + 2]; v[3] = acc2[4 * g + 3];
            v = __builtin_elementwise_max(v + b2v, z4);
            if (rbase + 3 < ROWSB) {
                p4 += v * w3v;
            } else {
#pragma unroll
                for (int rg = 0; rg < 4; ++rg)
                    if (rbase + rg < ROWSB) p4[rg] += v[rg] * w3v;
            }
        }
    }
    __syncthreads();   // WAR: H1s reused by next type
}

__global__ __launch_bounds__(256, 4)
void energy_kernel(const float* __restrict__ R, const int* __restrict__ seq,
                   const char* __restrict__ ws,
                   const float* b2_0, const float* b2_1, const float* b2_2,
                   const float* w3_0, const float* w3_1, const float* w3_2,
                   const float* b3_0, const float* b3_1, const float* b3_2,
                   float* __restrict__ out)
{
    __shared__ SMem sm;
    const int tid = threadIdx.x;
    const int b   = blockIdx.y;
    const int i0  = blockIdx.x * 128;
    const int lane = tid & 63, wv = tid >> 6;
    const int ln31 = lane & 31, hi = lane >> 5;

    // ---- stage R / seq / ebuf (once per block) ----
    for (int t = tid; t < 393; t += 256) {
        int lr = t / 3, comp = t - lr * 3;
        int row = min(i0 + lr, Lc - 1);
        sm.Rbuf[t] = R[((size_t)b * Lc + row) * 3 + comp];
    }
    for (int t = tid; t < 131; t += 256)
        sm.seqb[t] = seq[b * Lc + min(i0 + t, Lc - 1)];
    {
        const uint4* se = (const uint4*)(ws + 172032);
        for (int t = tid; t < 40; t += 256) ((uint4*)sm.ebuf)[t] = se[t];
    }
    __syncthreads();

    // ---- geometry -> packed bf16 header (once per block) ----
    if (tid < 128) {
        const float* p0 = &sm.Rbuf[tid * 3];
        float ax = p0[3] - p0[0], ay = p0[4] - p0[1], az = p0[5] - p0[2];
        float bx = p0[6] - p0[3], by = p0[7] - p0[4], bz = p0[8] - p0[5];
        float cx = p0[9] - p0[6], cy = p0[10] - p0[7], cz = p0[11] - p0[8];
        float na2 = ax * ax + ay * ay + az * az;
        float len = sqrtf(na2);
        float nb2 = bx * bx + by * by + bz * bz;
        float duv = -(ax * bx + ay * by + az * bz);
        float cost = fminf(fmaxf(duv / sqrtf(na2 * nb2), -1.0f), 1.0f);
        float n1x = ay * bz - az * by, n1y = az * bx - ax * bz, n1z = ax * by - ay * bx;
        float n2x = by * cz - bz * cy, n2y = bz * cx - bx * cz, n2z = bx * cy - by * cx;
        float binv = 1.0f / sqrtf(nb2);
        float ux = bx * binv, uy = by * binv, uz = bz * binv;
        float m1x = n1y * uz - n1z * uy, m1y = n1z * ux - n1x * uz, m1z = n1x * uy - n1y * ux;
        float yv = m1x * n2x + m1y * n2y + m1z * n2z;
        float xv = n1x * n2x + n1y * n2y + n1z * n2z;
        float inv = 1.0f / sqrtf(xv * xv + yv * yv);
        sm.geomh[tid] = make_uint2(pkbf(len, cost), pkbf(yv * inv, xv * inv));
    }
    __syncthreads();

    // ---- three type passes (2 barriers each) ----
    f32x4 p4 = (f32x4){0.f, 0.f, 0.f, 0.f};
    type_pass<0>(sm, ws, b2_0, w3_0, i0, wv, ln31, hi, p4);
    type_pass<1>(sm, ws, b2_1, w3_1, i0, wv, ln31, hi, p4);
    type_pass<2>(sm, ws, b2_2, w3_2, i0, wv, ln31, hi, p4);

    float p = p4[0] + p4[1] + p4[2] + p4[3];
#pragma unroll
    for (int off = 32; off > 0; off >>= 1)
        p += __shfl_down(p, off);
    if (lane == 0) sm.part[wv] = p;
    __syncthreads();
    if (tid == 0) {
        float tot = sm.part[0] + sm.part[1] + sm.part[2] + sm.part[3];
        tot += b3_0[0] * (float)min(Lc - 1 - i0, 128);
        tot += b3_1[0] * (float)min(Lc - 2 - i0, 128);
        tot += b3_2[0] * (float)min(Lc - 3 - i0, 128);
        atomicAdd(&out[b], tot);
    }
}

extern "C" void kernel_launch(void* const* d_in, const int* in_sizes, int n_in,
                              void* d_out, int out_size, void* d_ws, size_t ws_size,
                              hipStream_t stream) {
    const float* R   = (const float*)d_in[0];
    const int*   seq = (const int*)d_in[1];
    const float* emb = (const float*)d_in[2];
    float* out = (float*)d_out;
    char*  ws  = (char*)d_ws;

    prep_kernel<<<dim3(96), dim3(256), 0, stream>>>(
        (const float*)d_in[3],  (const float*)d_in[4],
        (const float*)d_in[9],  (const float*)d_in[10],
        (const float*)d_in[15], (const float*)d_in[16],
        (const float*)d_in[5],  (const float*)d_in[11], (const float*)d_in[17],
        emb, ws, out);

    dim3 grid(16, 128), block(256);
    energy_kernel<<<grid, block, 0, stream>>>(
        R, seq, ws,
        (const float*)d_in[6],  (const float*)d_in[12], (const float*)d_in[18],
        (const float*)d_in[7],  (const float*)d_in[13], (const float*)d_in[19],
        (const float*)d_in[8],  (const float*)d_in[14], (const float*)d_in[20],
        out);
}

// Round 13
// 169.076 us; speedup vs baseline: 1.1748x; 1.1748x over previous
//
#include <hip/hip_runtime.h>

// LocalEnergy R23: R15 exact pipeline (harness-verified best, 54.8us) at
// 512 threads/block: 8 waves each do HALF the R15 per-wave work.
// wave wv8 -> (hq = wv8&3: hid/col quarter, hh = wv8>>2: 64-row half).
// Same 2048 blocks, same 36.9KB LDS, same prologue, same GEMM shapes and
// fragment mappings -> weight streams stay L1-local (unlike R20's small
// blocks, which duplicated them across blocks). Residency: 4 blocks x 512
// = 2048 threads = HW cap (100% occupancy) at <=64 VGPR. Theory: R15's
// floor is latency with ~33% occupancy; doubling waves halves per-wave
// serial chains and doubles latency hiding. launch_bounds(512,4) = 128-reg
// cap (spill-safe per R13/R16/R19 lessons). B=128, L=2048, E=16, H=128.

typedef short bf16x8  __attribute__((ext_vector_type(8)));
typedef float f32x4   __attribute__((ext_vector_type(4)));
typedef float f32x16  __attribute__((ext_vector_type(16)));

constexpr int Lc  = 2048;

union FragU { uint4 u; bf16x8 v; };

__device__ __forceinline__ unsigned short f2bf(float f) {
    union { float f; unsigned u; } v; v.f = f;
    unsigned u = v.u;
    u = u + 0x7FFFu + ((u >> 16) & 1u);   // RTNE
    return (unsigned short)(u >> 16);
}

__device__ __forceinline__ unsigned pkbf(float a, float b) {
    unsigned ua = __float_as_uint(a) + 0x8000u;
    unsigned ub = __float_as_uint(b) + 0x8000u;
    return __builtin_amdgcn_perm(ub, ua, 0x07060302u);  // [lo=bf(a), hi=bf(b)]
}

// ws layout (bytes) — unchanged from R11/R15:
//   W2T[t] @ t*32768          : [col2=128][k=128] bf16 k-contig      (98304)
//   W1T[t] @ 98304 + t*24576  : [hid=128][k=96]   bf16 k-contig      (73728)
//     header slots: k0=len(t0), k1=cos_t(t1), k2=sin_p(t2), k3=cos_p(t2),
//     k4=b1, k16+j = embedding row j
//   EB     @ 172032           : [aa=20][16] bf16                     (640)
__global__ __launch_bounds__(256)
void prep_kernel(const float* __restrict__ W1_0, const float* __restrict__ b1_0,
                 const float* __restrict__ W1_1, const float* __restrict__ b1_1,
                 const float* __restrict__ W1_2, const float* __restrict__ b1_2,
                 const float* __restrict__ W2_0, const float* __restrict__ W2_1,
                 const float* __restrict__ W2_2,
                 const float* __restrict__ emb, char* __restrict__ ws,
                 float* __restrict__ out)
{
    const int tid = blockIdx.x * 256 + threadIdx.x;
    const int np  = gridDim.x * 256;
    if (blockIdx.x == 0 && threadIdx.x < 128) out[threadIdx.x] = 0.0f;

    unsigned short* d2 = (unsigned short*)ws;
    for (int o = tid; o < 3 * 16384; o += np) {
        int t = o >> 14, r = o & 16383, col = r >> 7, k = r & 127;
        const float* W2 = (t == 0) ? W2_0 : (t == 1) ? W2_1 : W2_2;
        d2[o] = f2bf(W2[k * 128 + col]);
    }
    unsigned short* d1 = (unsigned short*)(ws + 98304);
    for (int o = tid; o < 3 * 12288; o += np) {
        int t = o / 12288, r = o - t * 12288, hid = r / 96, k = r - hid * 96;
        const int NE16 = (t == 0) ? 32 : (t == 1) ? 48 : 64;
        const int NG   = (t == 2) ? 2 : 1;
        const float* W1 = (t == 0) ? W1_0 : (t == 1) ? W1_1 : W1_2;
        const float* b1 = (t == 0) ? b1_0 : (t == 1) ? b1_1 : b1_2;
        float v = 0.0f;
        if (k >= 16) {
            int j = k - 16;
            if (j < NE16) v = W1[(NG + j) * 128 + hid];
        } else if (k == 4) v = b1[hid];
        else if (t == 0 && k == 0) v = W1_0[hid];
        else if (t == 1 && k == 1) v = W1_1[hid];
        else if (t == 2 && k == 2) v = W1_2[hid];
        else if (t == 2 && k == 3) v = W1_2[128 + hid];
        d1[o] = f2bf(v);
    }
    unsigned short* eb = (unsigned short*)(ws + 172032);
    for (int i = tid; i < 320; i += np) eb[i] = f2bf(emb[i]);
}

struct SMem {
    unsigned short H1s[128 * 128];  // 32768 B, row stride 256B, XOR-swizzled
    float  Rbuf[393];               // 131 rows x 3
    uint2  geomh[128];              // packed bf16 header per row
    int    seqb[132];
    alignas(16) unsigned short ebuf[320];   // [20][16] bf16
    float  part[8];
};                                  // ~36.9 KB

// swizzled byte offset of H1[row][byte col]
__device__ __forceinline__ int h1_off(int row, int colb) {
    return row * 256 + (colb ^ ((row & 15) << 4));
}

template<int TYPE>
__device__ __forceinline__ void type_pass(
    SMem& sm, const char* __restrict__ ws,
    const float* __restrict__ b2, const float* __restrict__ w3,
    int i0, int hq, int hh, int ln31, int hi, f32x4& p4)
{
    constexpr int NEMB  = (TYPE == 0) ? 2 : (TYPE == 1) ? 3 : 4;
    constexpr int STEPS = 1 + NEMB;          // header + emb K-steps (K=16 each)
    constexpr int ROWSB = Lc - 1 - TYPE;

    const unsigned short* w1t = (const unsigned short*)(ws + 98304 + TYPE * 24576);
    const unsigned short* w2t = (const unsigned short*)(ws + TYPE * 32768);
    const f32x4 z4 = (f32x4){0.f, 0.f, 0.f, 0.f};

    // A1 frags for this wave's hid quarter: W1T[hq*32+ln31][k=s*16+hi*8 ..+8]
    FragU A1[STEPS];
#pragma unroll
    for (int s = 0; s < STEPS; ++s)
        A1[s].u = *(const uint4*)&w1t[(hq * 32 + ln31) * 96 + s * 16 + hi * 8];

    // ---- Phase 1: GEMM1 for this wave's 64-row half (2 row-tiles) ----
    f32x16 acc1[2];
    acc1[0] = (f32x16)(0.f);
    acc1[1] = (f32x16)(0.f);

#pragma unroll
    for (int s = 0; s < STEPS; ++s) {
#pragma unroll
        for (int rt = 0; rt < 2; ++rt) {
            const int row = hh * 64 + rt * 32 + ln31;
            FragU bb;
            if (s == 0) {                      // header [len,cos_t,sin_p,cos_p,1,0..]
                if (hi == 0) {
                    uint2 g = sm.geomh[row];
                    bb.u = make_uint4(g.x, g.y, 0x00003F80u, 0u);
                } else {
                    bb.u = make_uint4(0u, 0u, 0u, 0u);
                }
            } else {                           // embedding row j = s-1
                bb.u = *(const uint4*)&sm.ebuf[sm.seqb[row + (s - 1)] * 16 + hi * 8];
            }
            acc1[rt] = __builtin_amdgcn_mfma_f32_32x32x16_bf16(A1[s].v, bb.v, acc1[rt], 0, 0, 0);
        }
    }

    // H1 = relu -> H1s (swizzled). D: col=ln31=row, hid=(reg&3)+8*(reg>>2)+4*hi.
#pragma unroll
    for (int rt = 0; rt < 2; ++rt) {
        const int row = hh * 64 + rt * 32 + ln31;
#pragma unroll
        for (int g = 0; g < 4; ++g) {
            float v0 = fmaxf(acc1[rt][4 * g + 0], 0.f);
            float v1 = fmaxf(acc1[rt][4 * g + 1], 0.f);
            float v2 = fmaxf(acc1[rt][4 * g + 2], 0.f);
            float v3 = fmaxf(acc1[rt][4 * g + 3], 0.f);
            uint2 pk;
            pk.x = pkbf(v0, v1);
            pk.y = pkbf(v2, v3);
            *(uint2*)((char*)sm.H1s + h1_off(row, hq * 64 + 16 * g + 8 * hi)) = pk;
        }
    }

    // B2 frags + per-lane epilogue consts before the barrier (latency overlap)
    FragU B2[8];
#pragma unroll
    for (int s2 = 0; s2 < 8; ++s2)
        B2[s2].u = *(const uint4*)&w2t[(hq * 32 + ln31) * 128 + s2 * 16 + hi * 8];
    const float b2v = b2[hq * 32 + ln31];
    const float w3v = w3[hq * 32 + ln31];
    __syncthreads();   // H1s (all 128 rows) ready

    // ---- Phase 2: GEMM2 + epilogue for this wave's 64-row half ----
    f32x16 acc2[2];
    acc2[0] = (f32x16)(0.f);
    acc2[1] = (f32x16)(0.f);
#pragma unroll
    for (int s2 = 0; s2 < 8; ++s2)
#pragma unroll
        for (int rt = 0; rt < 2; ++rt) {
            const int row = hh * 64 + rt * 32 + ln31;
            bf16x8 aa = *(const bf16x8*)((const char*)sm.H1s +
                                         h1_off(row, s2 * 32 + hi * 16));
            acc2[rt] = __builtin_amdgcn_mfma_f32_32x32x16_bf16(aa, B2[s2].v, acc2[rt], 0, 0, 0);
        }

    // epilogue: p4 += relu(h2 + b2) * w3. D: col=ln31 (col2 = hq*32+ln31),
    // row = hh*64 + rt*32 + (reg&3) + 8*(reg>>2) + 4*hi.
#pragma unroll
    for (int rt = 0; rt < 2; ++rt) {
#pragma unroll
        for (int g = 0; g < 4; ++g) {
            const int rbase = i0 + hh * 64 + rt * 32 + 8 * g + 4 * hi;
            f32x4 v;
            v[0] = acc2[rt][4 * g + 0]; v[1] = acc2[rt][4 * g + 1];
            v[2] = acc2[rt][4 * g + 2]; v[3] = acc2[rt][4 * g + 3];
            v = __builtin_elementwise_max(v + b2v, z4);
            if (rbase + 3 < ROWSB) {
                p4 += v * w3v;
            } else {
#pragma unroll
                for (int rg = 0; rg < 4; ++rg)
                    if (rbase + rg < ROWSB) p4[rg] += v[rg] * w3v;
            }
        }
    }
    __syncthreads();   // WAR: H1s reused by next type
}

__global__ __launch_bounds__(512, 4)
void energy_kernel(const float* __restrict__ R, const int* __restrict__ seq,
                   const char* __restrict__ ws,
                   const float* b2_0, const float* b2_1, const float* b2_2,
                   const float* w3_0, const float* w3_1, const float* w3_2,
                   const float* b3_0, const float* b3_1, const float* b3_2,
                   float* __restrict__ out)
{
    __shared__ SMem sm;
    const int tid = threadIdx.x;
    const int b   = blockIdx.y;
    const int i0  = blockIdx.x * 128;
    const int lane = tid & 63, wv8 = tid >> 6;
    const int ln31 = lane & 31, hi = lane >> 5;
    const int hq = wv8 & 3, hh = wv8 >> 2;

    // ---- stage R / seq / ebuf (once per block) ----
    for (int t = tid; t < 393; t += 512) {
        int lr = t / 3, comp = t - lr * 3;
        int row = min(i0 + lr, Lc - 1);
        sm.Rbuf[t] = R[((size_t)b * Lc + row) * 3 + comp];
    }
    for (int t = tid; t < 131; t += 512)
        sm.seqb[t] = seq[b * Lc + min(i0 + t, Lc - 1)];
    {
        const uint4* se = (const uint4*)(ws + 172032);
        for (int t = tid; t < 40; t += 512) ((uint4*)sm.ebuf)[t] = se[t];
    }
    __syncthreads();

    // ---- geometry -> packed bf16 header (once per block) ----
    if (tid < 128) {
        const float* p0 = &sm.Rbuf[tid * 3];
        float ax = p0[3] - p0[0], ay = p0[4] - p0[1], az = p0[5] - p0[2];
        float bx = p0[6] - p0[3], by = p0[7] - p0[4], bz = p0[8] - p0[5];
        float cx = p0[9] - p0[6], cy = p0[10] - p0[7], cz = p0[11] - p0[8];
        float na2 = ax * ax + ay * ay + az * az;
        float len = sqrtf(na2);
        float nb2 = bx * bx + by * by + bz * bz;
        float duv = -(ax * bx + ay * by + az * bz);
        float cost = fminf(fmaxf(duv / sqrtf(na2 * nb2), -1.0f), 1.0f);
        float n1x = ay * bz - az * by, n1y = az * bx - ax * bz, n1z = ax * by - ay * bx;
        float n2x = by * cz - bz * cy, n2y = bz * cx - bx * cz, n2z = bx * cy - by * cx;
        float binv = 1.0f / sqrtf(nb2);
        float ux = bx * binv, uy = by * binv, uz = bz * binv;
        float m1x = n1y * uz - n1z * uy, m1y = n1z * ux - n1x * uz, m1z = n1x * uy - n1y * ux;
        float yv = m1x * n2x + m1y * n2y + m1z * n2z;
        float xv = n1x * n2x + n1y * n2y + n1z * n2z;
        float inv = 1.0f / sqrtf(xv * xv + yv * yv);
        sm.geomh[tid] = make_uint2(pkbf(len, cost), pkbf(yv * inv, xv * inv));
    }
    __syncthreads();

    // ---- three type passes (2 barriers each) ----
    f32x4 p4 = (f32x4){0.f, 0.f, 0.f, 0.f};
    type_pass<0>(sm, ws, b2_0, w3_0, i0, hq, hh, ln31, hi, p4);
    type_pass<1>(sm, ws, b2_1, w3_1, i0, hq, hh, ln31, hi, p4);
    type_pass<2>(sm, ws, b2_2, w3_2, i0, hq, hh, ln31, hi, p4);

    float p = p4[0] + p4[1] + p4[2] + p4[3];
#pragma unroll
    for (int off = 32; off > 0; off >>= 1)
        p += __shfl_down(p, off);
    if (lane == 0) sm.part[wv8] = p;
    __syncthreads();
    if (tid == 0) {
        float tot = 0.f;
#pragma unroll
        for (int w = 0; w < 8; ++w) tot += sm.part[w];
        tot += b3_0[0] * (float)min(Lc - 1 - i0, 128);
        tot += b3_1[0] * (float)min(Lc - 2 - i0, 128);
        tot += b3_2[0] * (float)min(Lc - 3 - i0, 128);
        atomicAdd(&out[b], tot);
    }
}

extern "C" void kernel_launch(void* const* d_in, const int* in_sizes, int n_in,
                              void* d_out, int out_size, void* d_ws, size_t ws_size,
                              hipStream_t stream) {
    const float* R   = (const float*)d_in[0];
    const int*   seq = (const int*)d_in[1];
    const float* emb = (const float*)d_in[2];
    float* out = (float*)d_out;
    char*  ws  = (char*)d_ws;

    prep_kernel<<<dim3(96), dim3(256), 0, stream>>>(
        (const float*)d_in[3],  (const float*)d_in[4],
        (const float*)d_in[9],  (const float*)d_in[10],
        (const float*)d_in[15], (const float*)d_in[16],
        (const float*)d_in[5],  (const float*)d_in[11], (const float*)d_in[17],
        emb, ws, out);

    dim3 grid(16, 128), block(512);
    energy_kernel<<<grid, block, 0, stream>>>(
        R, seq, ws,
        (const float*)d_in[6],  (const float*)d_in[12], (const float*)d_in[18],
        (const float*)d_in[7],  (const float*)d_in[13], (const float*)d_in[19],
        (const float*)d_in[8],  (const float*)d_in[14], (const float*)d_in[20],
        out);
}

// Round 14
// 148.526 us; speedup vs baseline: 1.3373x; 1.1384x over previous
//
#include <hip/hip_runtime.h>

// LocalEnergy R24: R15's math (harness-verified best, 54.8us) restructured as
// a software pipeline: H1 double-buffered at 64 rows ([2][64][128] bf16 =
// same 32KB), 7 segments over (type,half) pairs; each middle segment runs
// GEMM2(cur half) INTERLEAVED with GEMM1(next half) in one barrier-free
// region -> two independent MFMA chains + pack VALU + epilogue VALU
// co-scheduled by the compiler, attacking the ~25% phase-boundary stall that
// R15's barrier-serialized structure exposes. Total MFMA/bb/pack work and
// weight-load volume identical to R15 (A1/B2 1x per type). rt-sequential
// accumulators keep peak regs ~120-130; launch_bounds(256,3) = 168-reg cap
// (no spill -- session failure mode #1). TLP is pinned ~700 thr/CU on this
// kernel regardless of caps (R15/R16/R20/R23), so ILP is the lever.
// B=128, L=2048, E=16, H=128.

typedef short bf16x8  __attribute__((ext_vector_type(8)));
typedef float f32x4   __attribute__((ext_vector_type(4)));
typedef float f32x16  __attribute__((ext_vector_type(16)));

constexpr int Lc  = 2048;

union FragU { uint4 u; bf16x8 v; };

__device__ __forceinline__ unsigned short f2bf(float f) {
    union { float f; unsigned u; } v; v.f = f;
    unsigned u = v.u;
    u = u + 0x7FFFu + ((u >> 16) & 1u);   // RTNE
    return (unsigned short)(u >> 16);
}

__device__ __forceinline__ unsigned pkbf(float a, float b) {
    unsigned ua = __float_as_uint(a) + 0x8000u;
    unsigned ub = __float_as_uint(b) + 0x8000u;
    return __builtin_amdgcn_perm(ub, ua, 0x07060302u);  // [lo=bf(a), hi=bf(b)]
}

// ws layout (bytes) — unchanged from R11/R15:
//   W2T[t] @ t*32768          : [col2=128][k=128] bf16 k-contig      (98304)
//   W1T[t] @ 98304 + t*24576  : [hid=128][k=96]   bf16 k-contig      (73728)
//     header slots: k0=len(t0), k1=cos_t(t1), k2=sin_p(t2), k3=cos_p(t2),
//     k4=b1, k16+j = embedding row j
//   EB     @ 172032           : [aa=20][16] bf16                     (640)
__global__ __launch_bounds__(256)
void prep_kernel(const float* __restrict__ W1_0, const float* __restrict__ b1_0,
                 const float* __restrict__ W1_1, const float* __restrict__ b1_1,
                 const float* __restrict__ W1_2, const float* __restrict__ b1_2,
                 const float* __restrict__ W2_0, const float* __restrict__ W2_1,
                 const float* __restrict__ W2_2,
                 const float* __restrict__ emb, char* __restrict__ ws,
                 float* __restrict__ out)
{
    const int tid = blockIdx.x * 256 + threadIdx.x;
    const int np  = gridDim.x * 256;
    if (blockIdx.x == 0 && threadIdx.x < 128) out[threadIdx.x] = 0.0f;

    unsigned short* d2 = (unsigned short*)ws;
    for (int o = tid; o < 3 * 16384; o += np) {
        int t = o >> 14, r = o & 16383, col = r >> 7, k = r & 127;
        const float* W2 = (t == 0) ? W2_0 : (t == 1) ? W2_1 : W2_2;
        d2[o] = f2bf(W2[k * 128 + col]);
    }
    unsigned short* d1 = (unsigned short*)(ws + 98304);
    for (int o = tid; o < 3 * 12288; o += np) {
        int t = o / 12288, r = o - t * 12288, hid = r / 96, k = r - hid * 96;
        const int NE16 = (t == 0) ? 32 : (t == 1) ? 48 : 64;
        const int NG   = (t == 2) ? 2 : 1;
        const float* W1 = (t == 0) ? W1_0 : (t == 1) ? W1_1 : W1_2;
        const float* b1 = (t == 0) ? b1_0 : (t == 1) ? b1_1 : b1_2;
        float v = 0.0f;
        if (k >= 16) {
            int j = k - 16;
            if (j < NE16) v = W1[(NG + j) * 128 + hid];
        } else if (k == 4) v = b1[hid];
        else if (t == 0 && k == 0) v = W1_0[hid];
        else if (t == 1 && k == 1) v = W1_1[hid];
        else if (t == 2 && k == 2) v = W1_2[hid];
        else if (t == 2 && k == 3) v = W1_2[128 + hid];
        d1[o] = f2bf(v);
    }
    unsigned short* eb = (unsigned short*)(ws + 172032);
    for (int i = tid; i < 320; i += np) eb[i] = f2bf(emb[i]);
}

struct SMem {
    unsigned short H1s[2 * 64 * 128];  // 2 x 16KB half-buffers, XOR-swizzled
    float  Rbuf[393];                  // 131 rows x 3
    uint2  geomh[128];                 // packed bf16 header per row
    int    seqb[132];
    alignas(16) unsigned short ebuf[320];   // [20][16] bf16
    float  part[4];
};                                     // ~36.6 KB

// swizzled byte offset of H1[local row lr][byte col] within one half-buffer
__device__ __forceinline__ int h1_off(int lr, int colb) {
    return lr * 256 + (colb ^ ((lr & 15) << 4));
}

template<int TYPE>
__device__ __forceinline__ void load_A1(FragU* A1, const char* __restrict__ ws,
                                        int wv, int ln31, int hi) {
    constexpr int STEPS = 1 + ((TYPE == 0) ? 2 : (TYPE == 1) ? 3 : 4);
    const unsigned short* w1t = (const unsigned short*)(ws + 98304 + TYPE * 24576);
#pragma unroll
    for (int s = 0; s < STEPS; ++s)
        A1[s].u = *(const uint4*)&w1t[(wv * 32 + ln31) * 96 + s * 16 + hi * 8];
}

__device__ __forceinline__ void load_B2(FragU* B2, const char* __restrict__ ws,
                                        int type, int wv, int ln31, int hi) {
    const unsigned short* w2t = (const unsigned short*)(ws + type * 32768);
#pragma unroll
    for (int s2 = 0; s2 < 8; ++s2)
        B2[s2].u = *(const uint4*)&w2t[(wv * 32 + ln31) * 128 + s2 * 16 + hi * 8];
}

// GEMM1 for one 64-row half -> H1s[buf] (rt-sequential: acc1 = 16 regs)
template<int TYPE>
__device__ __forceinline__ void g1_half(SMem& sm, const FragU* A1,
                                        int h, int buf, int wv, int ln31, int hi) {
    constexpr int STEPS = 1 + ((TYPE == 0) ? 2 : (TYPE == 1) ? 3 : 4);
    char* h1b = (char*)sm.H1s + buf * 16384;
#pragma unroll
    for (int rt = 0; rt < 2; ++rt) {
        const int lr  = rt * 32 + ln31;     // local row in half
        const int row = h * 64 + lr;        // block-local row
        f32x16 acc1 = (f32x16)(0.f);
#pragma unroll
        for (int s = 0; s < STEPS; ++s) {
            FragU bb;
            if (s == 0) {                   // header [len,cos_t,sin_p,cos_p,1,0..]
                if (hi == 0) {
                    uint2 g = sm.geomh[row];
                    bb.u = make_uint4(g.x, g.y, 0x00003F80u, 0u);
                } else {
                    bb.u = make_uint4(0u, 0u, 0u, 0u);
                }
            } else {                        // embedding row j = s-1
                bb.u = *(const uint4*)&sm.ebuf[sm.seqb[row + (s - 1)] * 16 + hi * 8];
            }
            acc1 = __builtin_amdgcn_mfma_f32_32x32x16_bf16(A1[s].v, bb.v, acc1, 0, 0, 0);
        }
        // relu + pack. D: col=ln31=row, hid=(reg&3)+8*(reg>>2)+4*hi (+wv*32).
#pragma unroll
        for (int g = 0; g < 4; ++g) {
            float v0 = fmaxf(acc1[4 * g + 0], 0.f);
            float v1 = fmaxf(acc1[4 * g + 1], 0.f);
            float v2 = fmaxf(acc1[4 * g + 2], 0.f);
            float v3 = fmaxf(acc1[4 * g + 3], 0.f);
            uint2 pk;
            pk.x = pkbf(v0, v1);
            pk.y = pkbf(v2, v3);
            *(uint2*)(h1b + h1_off(lr, wv * 64 + 16 * g + 8 * hi)) = pk;
        }
    }
}

// GEMM2 + epilogue for one 64-row half from H1s[buf] (rt-sequential)
template<int TYPE>
__device__ __forceinline__ void g2_half(SMem& sm, const FragU* B2,
                                        float b2v, float w3v, int i0,
                                        int h, int buf, int wv, int ln31, int hi,
                                        f32x4& p4) {
    constexpr int ROWSB = Lc - 1 - TYPE;
    const f32x4 z4 = (f32x4){0.f, 0.f, 0.f, 0.f};
    const char* h1b = (const char*)sm.H1s + buf * 16384;
#pragma unroll
    for (int rt = 0; rt < 2; ++rt) {
        const int lr = rt * 32 + ln31;
        f32x16 acc2 = (f32x16)(0.f);
#pragma unroll
        for (int s2 = 0; s2 < 8; ++s2) {
            bf16x8 aa = *(const bf16x8*)(h1b + h1_off(lr, s2 * 32 + hi * 16));
            acc2 = __builtin_amdgcn_mfma_f32_32x32x16_bf16(aa, B2[s2].v, acc2, 0, 0, 0);
        }
        // epilogue: p4 += relu(h2 + b2) * w3. D: col=ln31=col2,
        // row = h*64 + rt*32 + (reg&3) + 8*(reg>>2) + 4*hi.
#pragma unroll
        for (int g = 0; g < 4; ++g) {
            const int rbase = i0 + h * 64 + rt * 32 + 8 * g + 4 * hi;
            f32x4 v;
            v[0] = acc2[4 * g + 0]; v[1] = acc2[4 * g + 1];
            v[2] = acc2[4 * g + 2]; v[3] = acc2[4 * g + 3];
            v = __builtin_elementwise_max(v + b2v, z4);
            if (rbase + 3 < ROWSB) {
                p4 += v * w3v;
            } else {
#pragma unroll
                for (int rg = 0; rg < 4; ++rg)
                    if (rbase + rg < ROWSB) p4[rg] += v[rg] * w3v;
            }
        }
    }
}

__global__ __launch_bounds__(256, 3)
void energy_kernel(const float* __restrict__ R, const int* __restrict__ seq,
                   const char* __restrict__ ws,
                   const float* b2_0, const float* b2_1, const float* b2_2,
                   const float* w3_0, const float* w3_1, const float* w3_2,
                   const float* b3_0, const float* b3_1, const float* b3_2,
                   float* __restrict__ out)
{
    __shared__ SMem sm;
    const int tid = threadIdx.x;
    const int b   = blockIdx.y;
    const int i0  = blockIdx.x * 128;
    const int lane = tid & 63, wv = tid >> 6;
    const int ln31 = lane & 31, hi = lane >> 5;

    // ---- stage R / seq / ebuf (once per block) ----
    for (int t = tid; t < 393; t += 256) {
        int lr = t / 3, comp = t - lr * 3;
        int row = min(i0 + lr, Lc - 1);
        sm.Rbuf[t] = R[((size_t)b * Lc + row) * 3 + comp];
    }
    for (int t = tid; t < 131; t += 256)
        sm.seqb[t] = seq[b * Lc + min(i0 + t, Lc - 1)];
    {
        const uint4* se = (const uint4*)(ws + 172032);
        for (int t = tid; t < 40; t += 256) ((uint4*)sm.ebuf)[t] = se[t];
    }
    __syncthreads();

    // ---- geometry -> packed bf16 header (once per block) ----
    if (tid < 128) {
        const float* p0 = &sm.Rbuf[tid * 3];
        float ax = p0[3] - p0[0], ay = p0[4] - p0[1], az = p0[5] - p0[2];
        float bx = p0[6] - p0[3], by = p0[7] - p0[4], bz = p0[8] - p0[5];
        float cx = p0[9] - p0[6], cy = p0[10] - p0[7], cz = p0[11] - p0[8];
        float na2 = ax * ax + ay * ay + az * az;
        float len = sqrtf(na2);
        float nb2 = bx * bx + by * by + bz * bz;
        float duv = -(ax * bx + ay * by + az * bz);
        float cost = fminf(fmaxf(duv / sqrtf(na2 * nb2), -1.0f), 1.0f);
        float n1x = ay * bz - az * by, n1y = az * bx - ax * bz, n1z = ax * by - ay * bx;
        float n2x = by * cz - bz * cy, n2y = bz * cx - bx * cz, n2z = bx * cy - by * cx;
        float binv = 1.0f / sqrtf(nb2);
        float ux = bx * binv, uy = by * binv, uz = bz * binv;
        float m1x = n1y * uz - n1z * uy, m1y = n1z * ux - n1x * uz, m1z = n1x * uy - n1y * ux;
        float yv = m1x * n2x + m1y * n2y + m1z * n2z;
        float xv = n1x * n2x + n1y * n2y + n1z * n2z;
        float inv = 1.0f / sqrtf(xv * xv + yv * yv);
        sm.geomh[tid] = make_uint2(pkbf(len, cost), pkbf(yv * inv, xv * inv));
    }
    __syncthreads();

    // ---- 7-segment software pipeline over (type, half) ----
    f32x4 p4 = (f32x4){0.f, 0.f, 0.f, 0.f};
    FragU A1[5], B2[8];
    float b2v, w3v;

    load_A1<0>(A1, ws, wv, ln31, hi);
    // S0: fill buf0 with type0/h0
    g1_half<0>(sm, A1, 0, 0, wv, ln31, hi);
    load_B2(B2, ws, 0, wv, ln31, hi);
    b2v = b2_0[wv * 32 + ln31]; w3v = w3_0[wv * 32 + ln31];
    __syncthreads();

    // S1: g2 t0/h0 (buf0) || g1 t0/h1 -> buf1
    g2_half<0>(sm, B2, b2v, w3v, i0, 0, 0, wv, ln31, hi, p4);
    g1_half<0>(sm, A1, 1, 1, wv, ln31, hi);
    load_A1<1>(A1, ws, wv, ln31, hi);          // type0 g1 done
    __syncthreads();

    // S2: g2 t0/h1 (buf1) || g1 t1/h0 -> buf0
    g2_half<0>(sm, B2, b2v, w3v, i0, 1, 1, wv, ln31, hi, p4);
    g1_half<1>(sm, A1, 0, 0, wv, ln31, hi);
    load_B2(B2, ws, 1, wv, ln31, hi);          // type0 g2 done
    b2v = b2_1[wv * 32 + ln31]; w3v = w3_1[wv * 32 + ln31];
    __syncthreads();

    // S3: g2 t1/h0 (buf0) || g1 t1/h1 -> buf1
    g2_half<1>(sm, B2, b2v, w3v, i0, 0, 0, wv, ln31, hi, p4);
    g1_half<1>(sm, A1, 1, 1, wv, ln31, hi);
    load_A1<2>(A1, ws, wv, ln31, hi);          // type1 g1 done
    __syncthreads();

    // S4: g2 t1/h1 (buf1) || g1 t2/h0 -> buf0
    g2_half<1>(sm, B2, b2v, w3v, i0, 1, 1, wv, ln31, hi, p4);
    g1_half<2>(sm, A1, 0, 0, wv, ln31, hi);
    load_B2(B2, ws, 2, wv, ln31, hi);          // type1 g2 done
    b2v = b2_2[wv * 32 + ln31]; w3v = w3_2[wv * 32 + ln31];
    __syncthreads();

    // S5: g2 t2/h0 (buf0) || g1 t2/h1 -> buf1
    g2_half<2>(sm, B2, b2v, w3v, i0, 0, 0, wv, ln31, hi, p4);
    g1_half<2>(sm, A1, 1, 1, wv, ln31, hi);
    __syncthreads();

    // S6: g2 t2/h1 (buf1)
    g2_half<2>(sm, B2, b2v, w3v, i0, 1, 1, wv, ln31, hi, p4);

    // ---- reduce ----
    float p = p4[0] + p4[1] + p4[2] + p4[3];
#pragma unroll
    for (int off = 32; off > 0; off >>= 1)
        p += __shfl_down(p, off);
    if (lane == 0) sm.part[wv] = p;
    __syncthreads();
    if (tid == 0) {
        float tot = sm.part[0] + sm.part[1] + sm.part[2] + sm.part[3];
        tot += b3_0[0] * (float)min(Lc - 1 - i0, 128);
        tot += b3_1[0] * (float)min(Lc - 2 - i0, 128);
        tot += b3_2[0] * (float)min(Lc - 3 - i0, 128);
        atomicAdd(&out[b], tot);
    }
}

extern "C" void kernel_launch(void* const* d_in, const int* in_sizes, int n_in,
                              void* d_out, int out_size, void* d_ws, size_t ws_size,
                              hipStream_t stream) {
    const float* R   = (const float*)d_in[0];
    const int*   seq = (const int*)d_in[1];
    const float* emb = (const float*)d_in[2];
    float* out = (float*)d_out;
    char*  ws  = (char*)d_ws;

    prep_kernel<<<dim3(96), dim3(256), 0, stream>>>(
        (const float*)d_in[3],  (const float*)d_in[4],
        (const float*)d_in[9],  (const float*)d_in[10],
        (const float*)d_in[15], (const float*)d_in[16],
        (const float*)d_in[5],  (const float*)d_in[11], (const float*)d_in[17],
        emb, ws, out);

    dim3 grid(16, 128), block(256);
    energy_kernel<<<grid, block, 0, stream>>>(
        R, seq, ws,
        (const float*)d_in[6],  (const float*)d_in[12], (const float*)d_in[18],
        (const float*)d_in[7],  (const float*)d_in[13], (const float*)d_in[19],
        (const float*)d_in[8],  (const float*)d_in[14], (const float*)d_in[20],
        out);
}

// Round 15
// 146.079 us; speedup vs baseline: 1.3597x; 1.0168x over previous
//
#include <hip/hip_runtime.h>

// LocalEnergy R25: R15 exact pipeline (harness-verified best, 54.8us) at 256
// rows/block (grid 8x128 = 1024 blocks), types-outer / chunks-inner:
// ONE prologue (R/seq/ebuf stage + geom chain, previously ~1.5-2us and run
// 2x) and ONE A1-load per type now serve two 128-row chunks. B2/b2v/w3v are
// reloaded per chunk at R15's exact pre-barrier placement (keeps R15's
// verified register live ranges -- R16's B2-hoist spill lesson). Per-chunk
// GEMM1/GEMM2/swizzle/pack identical to R15. Cost model: fixed ~5-8us/block
// (prologue + ramp quantization) amortized over 2x rows; rounds/CU 3.07->1.6.
// LDS ~38.8KB -> still 4 blocks/CU. launch_bounds(256,4) as R15.
// B=128, L=2048, E=16, H=128.

typedef short bf16x8  __attribute__((ext_vector_type(8)));
typedef float f32x4   __attribute__((ext_vector_type(4)));
typedef float f32x16  __attribute__((ext_vector_type(16)));

constexpr int Lc  = 2048;

union FragU { uint4 u; bf16x8 v; };

__device__ __forceinline__ unsigned short f2bf(float f) {
    union { float f; unsigned u; } v; v.f = f;
    unsigned u = v.u;
    u = u + 0x7FFFu + ((u >> 16) & 1u);   // RTNE
    return (unsigned short)(u >> 16);
}

__device__ __forceinline__ unsigned pkbf(float a, float b) {
    unsigned ua = __float_as_uint(a) + 0x8000u;
    unsigned ub = __float_as_uint(b) + 0x8000u;
    return __builtin_amdgcn_perm(ub, ua, 0x07060302u);  // [lo=bf(a), hi=bf(b)]
}

// ws layout (bytes) — unchanged from R11/R15:
//   W2T[t] @ t*32768          : [col2=128][k=128] bf16 k-contig      (98304)
//   W1T[t] @ 98304 + t*24576  : [hid=128][k=96]   bf16 k-contig      (73728)
//     header slots: k0=len(t0), k1=cos_t(t1), k2=sin_p(t2), k3=cos_p(t2),
//     k4=b1, k16+j = embedding row j
//   EB     @ 172032           : [aa=20][16] bf16                     (640)
__global__ __launch_bounds__(256)
void prep_kernel(const float* __restrict__ W1_0, const float* __restrict__ b1_0,
                 const float* __restrict__ W1_1, const float* __restrict__ b1_1,
                 const float* __restrict__ W1_2, const float* __restrict__ b1_2,
                 const float* __restrict__ W2_0, const float* __restrict__ W2_1,
                 const float* __restrict__ W2_2,
                 const float* __restrict__ emb, char* __restrict__ ws,
                 float* __restrict__ out)
{
    const int tid = blockIdx.x * 256 + threadIdx.x;
    const int np  = gridDim.x * 256;
    if (blockIdx.x == 0 && threadIdx.x < 128) out[threadIdx.x] = 0.0f;

    unsigned short* d2 = (unsigned short*)ws;
    for (int o = tid; o < 3 * 16384; o += np) {
        int t = o >> 14, r = o & 16383, col = r >> 7, k = r & 127;
        const float* W2 = (t == 0) ? W2_0 : (t == 1) ? W2_1 : W2_2;
        d2[o] = f2bf(W2[k * 128 + col]);
    }
    unsigned short* d1 = (unsigned short*)(ws + 98304);
    for (int o = tid; o < 3 * 12288; o += np) {
        int t = o / 12288, r = o - t * 12288, hid = r / 96, k = r - hid * 96;
        const int NE16 = (t == 0) ? 32 : (t == 1) ? 48 : 64;
        const int NG   = (t == 2) ? 2 : 1;
        const float* W1 = (t == 0) ? W1_0 : (t == 1) ? W1_1 : W1_2;
        const float* b1 = (t == 0) ? b1_0 : (t == 1) ? b1_1 : b1_2;
        float v = 0.0f;
        if (k >= 16) {
            int j = k - 16;
            if (j < NE16) v = W1[(NG + j) * 128 + hid];
        } else if (k == 4) v = b1[hid];
        else if (t == 0 && k == 0) v = W1_0[hid];
        else if (t == 1 && k == 1) v = W1_1[hid];
        else if (t == 2 && k == 2) v = W1_2[hid];
        else if (t == 2 && k == 3) v = W1_2[128 + hid];
        d1[o] = f2bf(v);
    }
    unsigned short* eb = (unsigned short*)(ws + 172032);
    for (int i = tid; i < 320; i += np) eb[i] = f2bf(emb[i]);
}

struct SMem {
    unsigned short H1s[128 * 128];  // 32768 B, row stride 256B, XOR-swizzled
    float  Rbuf[777];               // 259 rows x 3
    uint2  geomh[256];              // packed bf16 header per row (256 rows)
    int    seqb[260];
    alignas(16) unsigned short ebuf[320];   // [20][16] bf16
    float  part[4];
};                                  // ~38.8 KB

// swizzled byte offset of H1[chunk-local row][byte col]
__device__ __forceinline__ int h1_off(int row, int colb) {
    return row * 256 + (colb ^ ((row & 15) << 4));
}

template<int TYPE>
__device__ __forceinline__ void type_pass(
    SMem& sm, const char* __restrict__ ws,
    const float* __restrict__ b2, const float* __restrict__ w3,
    int i0, int wv, int ln31, int hi, f32x4& p4)
{
    constexpr int NEMB  = (TYPE == 0) ? 2 : (TYPE == 1) ? 3 : 4;
    constexpr int STEPS = 1 + NEMB;          // header + emb K-steps (K=16 each)
    constexpr int ROWSB = Lc - 1 - TYPE;

    const unsigned short* w1t = (const unsigned short*)(ws + 98304 + TYPE * 24576);
    const unsigned short* w2t = (const unsigned short*)(ws + TYPE * 32768);
    const f32x4 z4 = (f32x4){0.f, 0.f, 0.f, 0.f};

    // A1 frags loaded ONCE per type, reused by both 128-row chunks
    FragU A1[STEPS];
#pragma unroll
    for (int s = 0; s < STEPS; ++s)
        A1[s].u = *(const uint4*)&w1t[(wv * 32 + ln31) * 96 + s * 16 + hi * 8];

#pragma unroll
    for (int c = 0; c < 2; ++c) {
        const int rb = c * 128;              // block-local chunk base

        // ---- Phase 1: GEMM1 over both 64-row halves of this chunk ----
#pragma unroll
        for (int h = 0; h < 2; ++h) {
            f32x16 acc1[2];
            acc1[0] = (f32x16)(0.f);
            acc1[1] = (f32x16)(0.f);

#pragma unroll
            for (int s = 0; s < STEPS; ++s) {
#pragma unroll
                for (int rt = 0; rt < 2; ++rt) {
                    const int row = h * 64 + rt * 32 + ln31;   // chunk-local
                    const int bl  = rb + row;                  // block-local
                    FragU bb;
                    if (s == 0) {                  // header [len,cos_t,sin_p,cos_p,1,..]
                        if (hi == 0) {
                            uint2 g = sm.geomh[bl];
                            bb.u = make_uint4(g.x, g.y, 0x00003F80u, 0u);
                        } else {
                            bb.u = make_uint4(0u, 0u, 0u, 0u);
                        }
                    } else {                       // embedding row j = s-1
                        bb.u = *(const uint4*)&sm.ebuf[sm.seqb[bl + (s - 1)] * 16 + hi * 8];
                    }
                    acc1[rt] = __builtin_amdgcn_mfma_f32_32x32x16_bf16(A1[s].v, bb.v, acc1[rt], 0, 0, 0);
                }
            }

            // H1 = relu -> H1s (swizzled). D: col=ln31=row, hid=(reg&3)+8*(reg>>2)+4*hi.
#pragma unroll
            for (int rt = 0; rt < 2; ++rt) {
                const int row = h * 64 + rt * 32 + ln31;
#pragma unroll
                for (int g = 0; g < 4; ++g) {
                    float v0 = fmaxf(acc1[rt][4 * g + 0], 0.f);
                    float v1 = fmaxf(acc1[rt][4 * g + 1], 0.f);
                    float v2 = fmaxf(acc1[rt][4 * g + 2], 0.f);
                    float v3 = fmaxf(acc1[rt][4 * g + 3], 0.f);
                    uint2 pk;
                    pk.x = pkbf(v0, v1);
                    pk.y = pkbf(v2, v3);
                    *(uint2*)((char*)sm.H1s + h1_off(row, wv * 64 + 16 * g + 8 * hi)) = pk;
                }
            }
        }

        // B2 frags + epilogue consts: R15's exact pre-barrier placement,
        // reloaded per chunk (keeps R15 live ranges; R16 spill lesson)
        FragU B2[8];
#pragma unroll
        for (int s2 = 0; s2 < 8; ++s2)
            B2[s2].u = *(const uint4*)&w2t[(wv * 32 + ln31) * 128 + s2 * 16 + hi * 8];
        const float b2v = b2[wv * 32 + ln31];
        const float w3v = w3[wv * 32 + ln31];
        __syncthreads();   // H1s (this chunk's 128 rows) ready

        // ---- Phase 2: GEMM2 + epilogue over both halves ----
#pragma unroll
        for (int h = 0; h < 2; ++h) {
            f32x16 acc2[2];
            acc2[0] = (f32x16)(0.f);
            acc2[1] = (f32x16)(0.f);
#pragma unroll
            for (int s2 = 0; s2 < 8; ++s2)
#pragma unroll
                for (int rt = 0; rt < 2; ++rt) {
                    const int row = h * 64 + rt * 32 + ln31;
                    bf16x8 aa = *(const bf16x8*)((const char*)sm.H1s +
                                                 h1_off(row, s2 * 32 + hi * 16));
                    acc2[rt] = __builtin_amdgcn_mfma_f32_32x32x16_bf16(aa, B2[s2].v, acc2[rt], 0, 0, 0);
                }

            // epilogue: p4 += relu(h2 + b2) * w3. D: col=ln31=col2,
            // row = rb + h*64 + rt*32 + (reg&3) + 8*(reg>>2) + 4*hi.
#pragma unroll
            for (int rt = 0; rt < 2; ++rt) {
#pragma unroll
                for (int g = 0; g < 4; ++g) {
                    const int rbase = i0 + rb + h * 64 + rt * 32 + 8 * g + 4 * hi;
                    f32x4 v;
                    v[0] = acc2[rt][4 * g + 0]; v[1] = acc2[rt][4 * g + 1];
                    v[2] = acc2[rt][4 * g + 2]; v[3] = acc2[rt][4 * g + 3];
                    v = __builtin_elementwise_max(v + b2v, z4);
                    if (rbase + 3 < ROWSB) {
                        p4 += v * w3v;
                    } else {
#pragma unroll
                        for (int rg = 0; rg < 4; ++rg)
                            if (rbase + rg < ROWSB) p4[rg] += v[rg] * w3v;
                    }
                }
            }
        }
        __syncthreads();   // WAR: H1s reused by next chunk / next type
    }
}

__global__ __launch_bounds__(256, 4)
void energy_kernel(const float* __restrict__ R, const int* __restrict__ seq,
                   const char* __restrict__ ws,
                   const float* b2_0, const float* b2_1, const float* b2_2,
                   const float* w3_0, const float* w3_1, const float* w3_2,
                   const float* b3_0, const float* b3_1, const float* b3_2,
                   float* __restrict__ out)
{
    __shared__ SMem sm;
    const int tid = threadIdx.x;
    const int b   = blockIdx.y;
    const int i0  = blockIdx.x * 256;
    const int lane = tid & 63, wv = tid >> 6;
    const int ln31 = lane & 31, hi = lane >> 5;

    // ---- stage R / seq / ebuf (ONCE per 256-row block) ----
    for (int t = tid; t < 777; t += 256) {
        int lr = t / 3, comp = t - lr * 3;
        int row = min(i0 + lr, Lc - 1);
        sm.Rbuf[t] = R[((size_t)b * Lc + row) * 3 + comp];
    }
    for (int t = tid; t < 259; t += 256)
        sm.seqb[t] = seq[b * Lc + min(i0 + t, Lc - 1)];
    {
        const uint4* se = (const uint4*)(ws + 172032);
        for (int t = tid; t < 40; t += 256) ((uint4*)sm.ebuf)[t] = se[t];
    }
    __syncthreads();

    // ---- geometry -> packed bf16 header (256 rows, 1 sweep) ----
    {
        const float* p0 = &sm.Rbuf[tid * 3];
        float ax = p0[3] - p0[0], ay = p0[4] - p0[1], az = p0[5] - p0[2];
        float bx = p0[6] - p0[3], by = p0[7] - p0[4], bz = p0[8] - p0[5];
        float cx = p0[9] - p0[6], cy = p0[10] - p0[7], cz = p0[11] - p0[8];
        float na2 = ax * ax + ay * ay + az * az;
        float len = sqrtf(na2);
        float nb2 = bx * bx + by * by + bz * bz;
        float duv = -(ax * bx + ay * by + az * bz);
        float cost = fminf(fmaxf(duv / sqrtf(na2 * nb2), -1.0f), 1.0f);
        float n1x = ay * bz - az * by, n1y = az * bx - ax * bz, n1z = ax * by - ay * bx;
        float n2x = by * cz - bz * cy, n2y = bz * cx - bx * cz, n2z = bx * cy - by * cx;
        float binv = 1.0f / sqrtf(nb2);
        float ux = bx * binv, uy = by * binv, uz = bz * binv;
        float m1x = n1y * uz - n1z * uy, m1y = n1z * ux - n1x * uz, m1z = n1x * uy - n1y * ux;
        float yv = m1x * n2x + m1y * n2y + m1z * n2z;
        float xv = n1x * n2x + n1y * n2y + n1z * n2z;
        float inv = 1.0f / sqrtf(xv * xv + yv * yv);
        sm.geomh[tid] = make_uint2(pkbf(len, cost), pkbf(yv * inv, xv * inv));
    }
    __syncthreads();

    // ---- three type passes (A1 shared across 2 chunks each) ----
    f32x4 p4 = (f32x4){0.f, 0.f, 0.f, 0.f};
    type_pass<0>(sm, ws, b2_0, w3_0, i0, wv, ln31, hi, p4);
    type_pass<1>(sm, ws, b2_1, w3_1, i0, wv, ln31, hi, p4);
    type_pass<2>(sm, ws, b2_2, w3_2, i0, wv, ln31, hi, p4);

    float p = p4[0] + p4[1] + p4[2] + p4[3];
#pragma unroll
    for (int off = 32; off > 0; off >>= 1)
        p += __shfl_down(p, off);
    if (lane == 0) sm.part[wv] = p;
    __syncthreads();
    if (tid == 0) {
        float tot = sm.part[0] + sm.part[1] + sm.part[2] + sm.part[3];
        tot += b3_0[0] * (float)min(Lc - 1 - i0, 256);
        tot += b3_1[0] * (float)min(Lc - 2 - i0, 256);
        tot += b3_2[0] * (float)min(Lc - 3 - i0, 256);
        atomicAdd(&out[b], tot);
    }
}

extern "C" void kernel_launch(void* const* d_in, const int* in_sizes, int n_in,
                              void* d_out, int out_size, void* d_ws, size_t ws_size,
                              hipStream_t stream) {
    const float* R   = (const float*)d_in[0];
    const int*   seq = (const int*)d_in[1];
    const float* emb = (const float*)d_in[2];
    float* out = (float*)d_out;
    char*  ws  = (char*)d_ws;

    prep_kernel<<<dim3(96), dim3(256), 0, stream>>>(
        (const float*)d_in[3],  (const float*)d_in[4],
        (const float*)d_in[9],  (const float*)d_in[10],
        (const float*)d_in[15], (const float*)d_in[16],
        (const float*)d_in[5],  (const float*)d_in[11], (const float*)d_in[17],
        emb, ws, out);

    dim3 grid(8, 128), block(256);
    energy_kernel<<<grid, block, 0, stream>>>(
        R, seq, ws,
        (const float*)d_in[6],  (const float*)d_in[12], (const float*)d_in[18],
        (const float*)d_in[7],  (const float*)d_in[13], (const float*)d_in[19],
        (const float*)d_in[8],  (const float*)d_in[14], (const float*)d_in[20],
        out);
}

// Round 16
// 144.850 us; speedup vs baseline: 1.3712x; 1.0085x over previous
//
#include <hip/hip_runtime.h>

// LocalEnergy R26: R25 exact (best measured: 54.0us energy) with ONE change:
// the chunk loop is a RUNTIME loop (#pragma unroll 1). R25's body = type_pass
// x3 instantiations x2 unrolled chunks ~= 24-30KB of code, at the edge of the
// 32KB I-cache with 4 resident blocks fetching from different phases. I-cache
// fetch stall is the last unfalsified mechanism for the all-pipes-idle
// profile (MFMA 28 / VALU 44 / HBM 0.8 / occ 31, with conflicts, barriers,
// TLP, ILP, grain, registers, decomposition all falsified R12-R24).
// De-unrolling halves static code to ~12-15KB. All chunk indices are affine
// in c, so per-iteration codegen is unchanged. B=128, L=2048, E=16, H=128.

typedef short bf16x8  __attribute__((ext_vector_type(8)));
typedef float f32x4   __attribute__((ext_vector_type(4)));
typedef float f32x16  __attribute__((ext_vector_type(16)));

constexpr int Lc  = 2048;

union FragU { uint4 u; bf16x8 v; };

__device__ __forceinline__ unsigned short f2bf(float f) {
    union { float f; unsigned u; } v; v.f = f;
    unsigned u = v.u;
    u = u + 0x7FFFu + ((u >> 16) & 1u);   // RTNE
    return (unsigned short)(u >> 16);
}

__device__ __forceinline__ unsigned pkbf(float a, float b) {
    unsigned ua = __float_as_uint(a) + 0x8000u;
    unsigned ub = __float_as_uint(b) + 0x8000u;
    return __builtin_amdgcn_perm(ub, ua, 0x07060302u);  // [lo=bf(a), hi=bf(b)]
}

// ws layout (bytes) — unchanged from R11/R15:
//   W2T[t] @ t*32768          : [col2=128][k=128] bf16 k-contig      (98304)
//   W1T[t] @ 98304 + t*24576  : [hid=128][k=96]   bf16 k-contig      (73728)
//     header slots: k0=len(t0), k1=cos_t(t1), k2=sin_p(t2), k3=cos_p(t2),
//     k4=b1, k16+j = embedding row j
//   EB     @ 172032           : [aa=20][16] bf16                     (640)
__global__ __launch_bounds__(256)
void prep_kernel(const float* __restrict__ W1_0, const float* __restrict__ b1_0,
                 const float* __restrict__ W1_1, const float* __restrict__ b1_1,
                 const float* __restrict__ W1_2, const float* __restrict__ b1_2,
                 const float* __restrict__ W2_0, const float* __restrict__ W2_1,
                 const float* __restrict__ W2_2,
                 const float* __restrict__ emb, char* __restrict__ ws,
                 float* __restrict__ out)
{
    const int tid = blockIdx.x * 256 + threadIdx.x;
    const int np  = gridDim.x * 256;
    if (blockIdx.x == 0 && threadIdx.x < 128) out[threadIdx.x] = 0.0f;

    unsigned short* d2 = (unsigned short*)ws;
    for (int o = tid; o < 3 * 16384; o += np) {
        int t = o >> 14, r = o & 16383, col = r >> 7, k = r & 127;
        const float* W2 = (t == 0) ? W2_0 : (t == 1) ? W2_1 : W2_2;
        d2[o] = f2bf(W2[k * 128 + col]);
    }
    unsigned short* d1 = (unsigned short*)(ws + 98304);
    for (int o = tid; o < 3 * 12288; o += np) {
        int t = o / 12288, r = o - t * 12288, hid = r / 96, k = r - hid * 96;
        const int NE16 = (t == 0) ? 32 : (t == 1) ? 48 : 64;
        const int NG   = (t == 2) ? 2 : 1;
        const float* W1 = (t == 0) ? W1_0 : (t == 1) ? W1_1 : W1_2;
        const float* b1 = (t == 0) ? b1_0 : (t == 1) ? b1_1 : b1_2;
        float v = 0.0f;
        if (k >= 16) {
            int j = k - 16;
            if (j < NE16) v = W1[(NG + j) * 128 + hid];
        } else if (k == 4) v = b1[hid];
        else if (t == 0 && k == 0) v = W1_0[hid];
        else if (t == 1 && k == 1) v = W1_1[hid];
        else if (t == 2 && k == 2) v = W1_2[hid];
        else if (t == 2 && k == 3) v = W1_2[128 + hid];
        d1[o] = f2bf(v);
    }
    unsigned short* eb = (unsigned short*)(ws + 172032);
    for (int i = tid; i < 320; i += np) eb[i] = f2bf(emb[i]);
}

struct SMem {
    unsigned short H1s[128 * 128];  // 32768 B, row stride 256B, XOR-swizzled
    float  Rbuf[777];               // 259 rows x 3
    uint2  geomh[256];              // packed bf16 header per row (256 rows)
    int    seqb[260];
    alignas(16) unsigned short ebuf[320];   // [20][16] bf16
    float  part[4];
};                                  // ~38.8 KB

// swizzled byte offset of H1[chunk-local row][byte col]
__device__ __forceinline__ int h1_off(int row, int colb) {
    return row * 256 + (colb ^ ((row & 15) << 4));
}

template<int TYPE>
__device__ __forceinline__ void type_pass(
    SMem& sm, const char* __restrict__ ws,
    const float* __restrict__ b2, const float* __restrict__ w3,
    int i0, int wv, int ln31, int hi, f32x4& p4)
{
    constexpr int NEMB  = (TYPE == 0) ? 2 : (TYPE == 1) ? 3 : 4;
    constexpr int STEPS = 1 + NEMB;          // header + emb K-steps (K=16 each)
    constexpr int ROWSB = Lc - 1 - TYPE;

    const unsigned short* w1t = (const unsigned short*)(ws + 98304 + TYPE * 24576);
    const unsigned short* w2t = (const unsigned short*)(ws + TYPE * 32768);
    const f32x4 z4 = (f32x4){0.f, 0.f, 0.f, 0.f};

    // A1 frags loaded ONCE per type, reused by both 128-row chunks
    FragU A1[STEPS];
#pragma unroll
    for (int s = 0; s < STEPS; ++s)
        A1[s].u = *(const uint4*)&w1t[(wv * 32 + ln31) * 96 + s * 16 + hi * 8];

#pragma unroll 1
    for (int c = 0; c < 2; ++c) {
        const int rb = c * 128;              // block-local chunk base

        // ---- Phase 1: GEMM1 over both 64-row halves of this chunk ----
#pragma unroll
        for (int h = 0; h < 2; ++h) {
            f32x16 acc1[2];
            acc1[0] = (f32x16)(0.f);
            acc1[1] = (f32x16)(0.f);

#pragma unroll
            for (int s = 0; s < STEPS; ++s) {
#pragma unroll
                for (int rt = 0; rt < 2; ++rt) {
                    const int row = h * 64 + rt * 32 + ln31;   // chunk-local
                    const int bl  = rb + row;                  // block-local
                    FragU bb;
                    if (s == 0) {                  // header [len,cos_t,sin_p,cos_p,1,..]
                        if (hi == 0) {
                            uint2 g = sm.geomh[bl];
                            bb.u = make_uint4(g.x, g.y, 0x00003F80u, 0u);
                        } else {
                            bb.u = make_uint4(0u, 0u, 0u, 0u);
                        }
                    } else {                       // embedding row j = s-1
                        bb.u = *(const uint4*)&sm.ebuf[sm.seqb[bl + (s - 1)] * 16 + hi * 8];
                    }
                    acc1[rt] = __builtin_amdgcn_mfma_f32_32x32x16_bf16(A1[s].v, bb.v, acc1[rt], 0, 0, 0);
                }
            }

            // H1 = relu -> H1s (swizzled). D: col=ln31=row, hid=(reg&3)+8*(reg>>2)+4*hi.
#pragma unroll
            for (int rt = 0; rt < 2; ++rt) {
                const int row = h * 64 + rt * 32 + ln31;
#pragma unroll
                for (int g = 0; g < 4; ++g) {
                    float v0 = fmaxf(acc1[rt][4 * g + 0], 0.f);
                    float v1 = fmaxf(acc1[rt][4 * g + 1], 0.f);
                    float v2 = fmaxf(acc1[rt][4 * g + 2], 0.f);
                    float v3 = fmaxf(acc1[rt][4 * g + 3], 0.f);
                    uint2 pk;
                    pk.x = pkbf(v0, v1);
                    pk.y = pkbf(v2, v3);
                    *(uint2*)((char*)sm.H1s + h1_off(row, wv * 64 + 16 * g + 8 * hi)) = pk;
                }
            }
        }

        // B2 frags + epilogue consts: R15's exact pre-barrier placement,
        // reloaded per chunk (keeps R15 live ranges; R16 spill lesson)
        FragU B2[8];
#pragma unroll
        for (int s2 = 0; s2 < 8; ++s2)
            B2[s2].u = *(const uint4*)&w2t[(wv * 32 + ln31) * 128 + s2 * 16 + hi * 8];
        const float b2v = b2[wv * 32 + ln31];
        const float w3v = w3[wv * 32 + ln31];
        __syncthreads();   // H1s (this chunk's 128 rows) ready

        // ---- Phase 2: GEMM2 + epilogue over both halves ----
#pragma unroll
        for (int h = 0; h < 2; ++h) {
            f32x16 acc2[2];
            acc2[0] = (f32x16)(0.f);
            acc2[1] = (f32x16)(0.f);
#pragma unroll
            for (int s2 = 0; s2 < 8; ++s2)
#pragma unroll
                for (int rt = 0; rt < 2; ++rt) {
                    const int row = h * 64 + rt * 32 + ln31;
                    bf16x8 aa = *(const bf16x8*)((const char*)sm.H1s +
                                                 h1_off(row, s2 * 32 + hi * 16));
                    acc2[rt] = __builtin_amdgcn_mfma_f32_32x32x16_bf16(aa, B2[s2].v, acc2[rt], 0, 0, 0);
                }

            // epilogue: p4 += relu(h2 + b2) * w3. D: col=ln31=col2,
            // row = rb + h*64 + rt*32 + (reg&3) + 8*(reg>>2) + 4*hi.
#pragma unroll
            for (int rt = 0; rt < 2; ++rt) {
#pragma unroll
                for (int g = 0; g < 4; ++g) {
                    const int rbase = i0 + rb + h * 64 + rt * 32 + 8 * g + 4 * hi;
                    f32x4 v;
                    v[0] = acc2[rt][4 * g + 0]; v[1] = acc2[rt][4 * g + 1];
                    v[2] = acc2[rt][4 * g + 2]; v[3] = acc2[rt][4 * g + 3];
                    v = __builtin_elementwise_max(v + b2v, z4);
                    if (rbase + 3 < ROWSB) {
                        p4 += v * w3v;
                    } else {
#pragma unroll
                        for (int rg = 0; rg < 4; ++rg)
                            if (rbase + rg < ROWSB) p4[rg] += v[rg] * w3v;
                    }
                }
            }
        }
        __syncthreads();   // WAR: H1s reused by next chunk / next type
    }
}

__global__ __launch_bounds__(256, 4)
void energy_kernel(const float* __restrict__ R, const int* __restrict__ seq,
                   const char* __restrict__ ws,
                   const float* b2_0, const float* b2_1, const float* b2_2,
                   const float* w3_0, const float* w3_1, const float* w3_2,
                   const float* b3_0, const float* b3_1, const float* b3_2,
                   float* __restrict__ out)
{
    __shared__ SMem sm;
    const int tid = threadIdx.x;
    const int b   = blockIdx.y;
    const int i0  = blockIdx.x * 256;
    const int lane = tid & 63, wv = tid >> 6;
    const int ln31 = lane & 31, hi = lane >> 5;

    // ---- stage R / seq / ebuf (ONCE per 256-row block) ----
    for (int t = tid; t < 777; t += 256) {
        int lr = t / 3, comp = t - lr * 3;
        int row = min(i0 + lr, Lc - 1);
        sm.Rbuf[t] = R[((size_t)b * Lc + row) * 3 + comp];
    }
    for (int t = tid; t < 259; t += 256)
        sm.seqb[t] = seq[b * Lc + min(i0 + t, Lc - 1)];
    {
        const uint4* se = (const uint4*)(ws + 172032);
        for (int t = tid; t < 40; t += 256) ((uint4*)sm.ebuf)[t] = se[t];
    }
    __syncthreads();

    // ---- geometry -> packed bf16 header (256 rows, 1 sweep) ----
    {
        const float* p0 = &sm.Rbuf[tid * 3];
        float ax = p0[3] - p0[0], ay = p0[4] - p0[1], az = p0[5] - p0[2];
        float bx = p0[6] - p0[3], by = p0[7] - p0[4], bz = p0[8] - p0[5];
        float cx = p0[9] - p0[6], cy = p0[10] - p0[7], cz = p0[11] - p0[8];
        float na2 = ax * ax + ay * ay + az * az;
        float len = sqrtf(na2);
        float nb2 = bx * bx + by * by + bz * bz;
        float duv = -(ax * bx + ay * by + az * bz);
        float cost = fminf(fmaxf(duv / sqrtf(na2 * nb2), -1.0f), 1.0f);
        float n1x = ay * bz - az * by, n1y = az * bx - ax * bz, n1z = ax * by - ay * bx;
        float n2x = by * cz - bz * cy, n2y = bz * cx - bx * cz, n2z = bx * cy - by * cx;
        float binv = 1.0f / sqrtf(nb2);
        float ux = bx * binv, uy = by * binv, uz = bz * binv;
        float m1x = n1y * uz - n1z * uy, m1y = n1z * ux - n1x * uz, m1z = n1x * uy - n1y * ux;
        float yv = m1x * n2x + m1y * n2y + m1z * n2z;
        float xv = n1x * n2x + n1y * n2y + n1z * n2z;
        float inv = 1.0f / sqrtf(xv * xv + yv * yv);
        sm.geomh[tid] = make_uint2(pkbf(len, cost), pkbf(yv * inv, xv * inv));
    }
    __syncthreads();

    // ---- three type passes (A1 shared across 2 chunks each) ----
    f32x4 p4 = (f32x4){0.f, 0.f, 0.f, 0.f};
    type_pass<0>(sm, ws, b2_0, w3_0, i0, wv, ln31, hi, p4);
    type_pass<1>(sm, ws, b2_1, w3_1, i0, wv, ln31, hi, p4);
    type_pass<2>(sm, ws, b2_2, w3_2, i0, wv, ln31, hi, p4);

    float p = p4[0] + p4[1] + p4[2] + p4[3];
#pragma unroll
    for (int off = 32; off > 0; off >>= 1)
        p += __shfl_down(p, off);
    if (lane == 0) sm.part[wv] = p;
    __syncthreads();
    if (tid == 0) {
        float tot = sm.part[0] + sm.part[1] + sm.part[2] + sm.part[3];
        tot += b3_0[0] * (float)min(Lc - 1 - i0, 256);
        tot += b3_1[0] * (float)min(Lc - 2 - i0, 256);
        tot += b3_2[0] * (float)min(Lc - 3 - i0, 256);
        atomicAdd(&out[b], tot);
    }
}

extern "C" void kernel_launch(void* const* d_in, const int* in_sizes, int n_in,
                              void* d_out, int out_size, void* d_ws, size_t ws_size,
                              hipStream_t stream) {
    const float* R   = (const float*)d_in[0];
    const int*   seq = (const int*)d_in[1];
    const float* emb = (const float*)d_in[2];
    float* out = (float*)d_out;
    char*  ws  = (char*)d_ws;

    prep_kernel<<<dim3(96), dim3(256), 0, stream>>>(
        (const float*)d_in[3],  (const float*)d_in[4],
        (const float*)d_in[9],  (const float*)d_in[10],
        (const float*)d_in[15], (const float*)d_in[16],
        (const float*)d_in[5],  (const float*)d_in[11], (const float*)d_in[17],
        emb, ws, out);

    dim3 grid(8, 128), block(256);
    energy_kernel<<<grid, block, 0, stream>>>(
        R, seq, ws,
        (const float*)d_in[6],  (const float*)d_in[12], (const float*)d_in[18],
        (const float*)d_in[7],  (const float*)d_in[13], (const float*)d_in[19],
        (const float*)d_in[8],  (const float*)d_in[14], (const float*)d_in[20],
        out);
}